// Round 12
// baseline (1360.223 us; speedup 1.0000x reference)
//
#include <hip/hip_runtime.h>
#include <cmath>

// Problem constants
constexpr int Bb  = 8;
constexpr int Tt  = 2048;
constexpr int DIN = 512;
constexpr int Dd  = 1024;
constexpr long long BT  = (long long)Bb * Tt;   // 16384
constexpr long long BTD = BT * Dd;              // 16777216

// ===== FROZEN NUMERICS (verified PASS rounds 9-11, absmax 0.03125) =========
__device__ __forceinline__ float np_expf(float x) {
  const float LOG2E = 1.4426950408889634074f;
  const float MAGIC = 12582912.0f;              // 0x1.8p23
  const float C1 = -6.93145752e-1f;
  const float C2 = -1.42860677e-6f;
  const float P0 = 9.999999999980870924916e-01f;
  const float P1 = 7.257664613233124478488e-01f;
  const float P2 = 2.473615434895520810817e-01f;
  const float P3 = 5.114512081637298353406e-02f;
  const float P4 = 6.757896990527504603057e-03f;
  const float P5 = 5.082762527590693718096e-04f;
  const float Q0 = 1.0f;
  const float Q1 = -2.742335390411667452936e-01f;
  const float Q2 = 2.159509375685829852307e-02f;
  const float XMAX = 88.72283935546875f;
  const float XMIN = -87.3365478515625f;
  if (!(x == x)) return x;
  if (x > XMAX)  return __builtin_inff();
  if (x < XMIN)  return 0.0f;
  float q = __fsub_rn(fmaf(x, LOG2E, MAGIC), MAGIC);
  float r = fmaf(q, C1, x);
  r = fmaf(q, C2, r);
  float num = fmaf(r, P5, P4);
  num = fmaf(num, r, P3);
  num = fmaf(num, r, P2);
  num = fmaf(num, r, P1);
  num = fmaf(num, r, P0);
  float den = fmaf(r, Q2, Q1);
  den = fmaf(den, r, Q0);
  float p = __fdiv_rn(num, den);
  return ldexpf(p, (int)q);
}

__device__ __forceinline__ float expf_cr(float x) { return (float)exp((double)x); }

__device__ __forceinline__ float log1pf_fd(float x) {
  const float ln2_hi = __int_as_float(0x3f317180);
  const float ln2_lo = __int_as_float(0x3717f7d1);
  const float Lp1 = __int_as_float(0x3F2AAAAB), Lp2 = __int_as_float(0x3ECCCCCD),
              Lp3 = __int_as_float(0x3E924925), Lp4 = __int_as_float(0x3E638E29),
              Lp5 = __int_as_float(0x3E3A3325), Lp6 = __int_as_float(0x3E1CD04F),
              Lp7 = __int_as_float(0x3E178897);
  int hx = __float_as_int(x);
  int ax = hx & 0x7fffffff;
  int k = 1, hu = 0;
  float f = 0.f, c = 0.f, u;
  if (hx < 0x3ed413d7) {
    if (ax < 0x38000000) {
      if (ax < 0x33800000) return x;
      return __fsub_rn(x, __fmul_rn(__fmul_rn(x, x), 0.5f));
    }
    if (hx > 0 || hx <= (int)0xbe95f61f) { k = 0; f = x; hu = 1; }
  }
  if (k != 0) {
    if (hx < 0x4b800000) {
      u = __fadd_rn(1.0f, x);
      int hu0 = __float_as_int(u);
      k = (hu0 >> 23) - 127;
      c = (k > 0) ? __fsub_rn(1.0f, __fsub_rn(u, x))
                  : __fsub_rn(x, __fsub_rn(u, 1.0f));
      c = __fdiv_rn(c, u);
      hu = hu0;
    } else {
      u = x; hu = __float_as_int(u); k = (hu >> 23) - 127; c = 0.f;
    }
    hu &= 0x007fffff;
    if (hu < 0x3504f7) { u = __int_as_float(hu | 0x3f800000); }
    else { k += 1; u = __int_as_float(hu | 0x3f000000); hu = (0x00800000 - hu) >> 2; }
    f = __fsub_rn(u, 1.0f);
  }
  float hfsq = __fmul_rn(__fmul_rn(0.5f, f), f);
  if (hu == 0) {
    if (f == 0.0f) {
      if (k == 0) return 0.0f;
      c = __fadd_rn(c, __fmul_rn((float)k, ln2_lo));
      return __fadd_rn(__fmul_rn((float)k, ln2_hi), c);
    }
    float R = __fmul_rn(hfsq, __fsub_rn(1.0f, __fmul_rn(0.66666668653f, f)));
    if (k == 0) return __fsub_rn(f, R);
    return __fsub_rn(__fmul_rn((float)k, ln2_hi),
           __fsub_rn(__fsub_rn(R, __fadd_rn(__fmul_rn((float)k, ln2_lo), c)), f));
  }
  float s = __fdiv_rn(f, __fadd_rn(2.0f, f));
  float z = __fmul_rn(s, s);
  float pz = __fadd_rn(Lp6, __fmul_rn(z, Lp7));
  pz = __fadd_rn(Lp5, __fmul_rn(z, pz));
  pz = __fadd_rn(Lp4, __fmul_rn(z, pz));
  pz = __fadd_rn(Lp3, __fmul_rn(z, pz));
  pz = __fadd_rn(Lp2, __fmul_rn(z, pz));
  pz = __fadd_rn(Lp1, __fmul_rn(z, pz));
  float R = __fmul_rn(z, pz);
  if (k == 0)
    return __fsub_rn(f, __fsub_rn(hfsq, __fmul_rn(s, __fadd_rn(hfsq, R))));
  return __fsub_rn(__fmul_rn((float)k, ln2_hi),
         __fsub_rn(__fsub_rn(hfsq, __fadd_rn(__fmul_rn(s, __fadd_rn(hfsq, R)),
                   __fadd_rn(__fmul_rn((float)k, ln2_lo), c))), f));
}

__device__ __forceinline__ float np_softplus(float x) {
  if (x == 0.0f) return __int_as_float(0x3F317218);
  if (x > 0.0f)  return __fadd_rn(x, log1pf_fd(expf_cr(-x)));
  return log1pf_fd(expf_cr(x));
}
// ===========================================================================

#define BM 128
#define BN 64
#define BK 32

// ---------------------------------------------------------------------------
// Kernel 1: dual GEMM — PURE ASCENDING TWO-ROUNDING CHAIN per output element.
// R10 structure (8x4 microtile, proven 605us) + two fixes:
//  - W LDS col swizzle: store col = n ^ (kq<<2); read b128 at 4*(tx^kq)
//    (scalar stage-writes 8-way -> 2-way; reads stay 2-way free)
//  - register-prefetch pipeline: issue kt+1 global loads before compute(kt)
// Per-element FP op sequence bit-identical to rounds 9/10.
// ---------------------------------------------------------------------------
__global__ __launch_bounds__(256, 4) void gemm_np(
    const float* __restrict__ x,  const float* __restrict__ Wd,
    const float* __restrict__ bd, const float* __restrict__ Wb,
    const float* __restrict__ bb, const float* __restrict__ A_log,
    float* __restrict__ Aarr, float* __restrict__ Barr)
{
  __shared__ float xs[BM][BK];      // [m][k], quad-swizzled within row
  __shared__ float wds[BK][BN];     // [k][n], col = n ^ (kq<<2)
  __shared__ float wbs[BK][BN];

  const int tid = threadIdx.x;
  const int bn0 = blockIdx.x * BN;
  const int bm0 = blockIdx.y * BM;
  const int tx  = tid & 15;         // n-quad: cols tx*4 .. +3
  const int mg  = tid >> 4;         // m-group 0..15: rows mg*8 .. +7
  const int swz = mg & 7;           // x read swizzle key

  // staging coords: f = p*256 + tid -> row/n = p*32 + (tid>>3), q = tid&7
  const int sr8 = tid >> 3;         // 0..31
  const int sq  = tid & 7;          // 0..7

  float accd[8][4], accb[8][4];
#pragma unroll
  for (int i = 0; i < 8; ++i)
#pragma unroll
    for (int j = 0; j < 4; ++j) { accd[i][j] = 0.f; accb[i][j] = 0.f; }

  // ---- prefetch registers (tile kt) ----
  float4 px0, px1, px2, px3, pd0, pd1, pb0, pb1;
#define ISSUE_LOADS(K0)                                                        \
  {                                                                            \
    const int k0_ = (K0);                                                      \
    px0 = *(const float4*)&x[(size_t)(bm0 +  0 + sr8) * DIN + k0_ + sq * 4];   \
    px1 = *(const float4*)&x[(size_t)(bm0 + 32 + sr8) * DIN + k0_ + sq * 4];   \
    px2 = *(const float4*)&x[(size_t)(bm0 + 64 + sr8) * DIN + k0_ + sq * 4];   \
    px3 = *(const float4*)&x[(size_t)(bm0 + 96 + sr8) * DIN + k0_ + sq * 4];   \
    pd0 = *(const float4*)&Wd[(size_t)(bn0 +  0 + sr8) * DIN + k0_ + sq * 4];  \
    pd1 = *(const float4*)&Wd[(size_t)(bn0 + 32 + sr8) * DIN + k0_ + sq * 4];  \
    pb0 = *(const float4*)&Wb[(size_t)(bn0 +  0 + sr8) * DIN + k0_ + sq * 4];  \
    pb1 = *(const float4*)&Wb[(size_t)(bn0 + 32 + sr8) * DIN + k0_ + sq * 4];  \
  }

  ISSUE_LOADS(0);

  for (int kt = 0; kt < DIN / BK; ++kt) {       // 16 k-tiles, ascending
    __syncthreads();                             // previous compute done
    // ---- write staged regs to LDS ----
    {
      // x: rows p*32+sr8, quad sq, swizzle qs = sq ^ ((row>>3)&7)
      int r0 = sr8,      qs0 = sq ^ ((r0 >> 3) & 7);
      int r1 = 32 + sr8, qs1 = sq ^ ((r1 >> 3) & 7);
      int r2 = 64 + sr8, qs2 = sq ^ ((r2 >> 3) & 7);
      int r3 = 96 + sr8, qs3 = sq ^ ((r3 >> 3) & 7);
      *(float4*)&xs[r0][qs0 * 4] = px0;
      *(float4*)&xs[r1][qs1 * 4] = px1;
      *(float4*)&xs[r2][qs2 * 4] = px2;
      *(float4*)&xs[r3][qs3 * 4] = px3;
      // W: n = p*32+sr8, kq = sq, col = n ^ (kq<<2)
      int c0 = (sr8)      ^ (sq << 2);
      int c1 = (32 + sr8) ^ (sq << 2);
      wds[sq*4+0][c0] = pd0.x; wds[sq*4+1][c0] = pd0.y;
      wds[sq*4+2][c0] = pd0.z; wds[sq*4+3][c0] = pd0.w;
      wds[sq*4+0][c1] = pd1.x; wds[sq*4+1][c1] = pd1.y;
      wds[sq*4+2][c1] = pd1.z; wds[sq*4+3][c1] = pd1.w;
      wbs[sq*4+0][c0] = pb0.x; wbs[sq*4+1][c0] = pb0.y;
      wbs[sq*4+2][c0] = pb0.z; wbs[sq*4+3][c0] = pb0.w;
      wbs[sq*4+0][c1] = pb1.x; wbs[sq*4+1][c1] = pb1.y;
      wbs[sq*4+2][c1] = pb1.z; wbs[sq*4+3][c1] = pb1.w;
    }
    __syncthreads();

    // ---- issue next tile's loads (latency hides under compute) ----
    if (kt + 1 < DIN / BK) ISSUE_LOADS((kt + 1) * BK);

    // ---- compute on LDS tile kt ----
#pragma unroll
    for (int kq = 0; kq < BK / 4; ++kq) {        // 8 quads, ascending
      float xk[8][4];
#pragma unroll
      for (int i = 0; i < 8; ++i) {
        float4 v = *(const float4*)&xs[mg * 8 + i][(kq ^ swz) * 4];
        xk[i][0] = v.x; xk[i][1] = v.y; xk[i][2] = v.z; xk[i][3] = v.w;
      }
      const int wc = 4 * (tx ^ kq);
#pragma unroll
      for (int t = 0; t < 4; ++t) {              // k within quad, ascending
        float4 wdv = *(const float4*)&wds[kq * 4 + t][wc];
        float4 wbv = *(const float4*)&wbs[kq * 4 + t][wc];
        float wd4[4] = {wdv.x, wdv.y, wdv.z, wdv.w};
        float wb4[4] = {wbv.x, wbv.y, wbv.z, wbv.w};
#pragma unroll
        for (int i = 0; i < 8; ++i) {
          const float xv = xk[i][t];
#pragma unroll
          for (int j = 0; j < 4; ++j) {
            accd[i][j] = __fadd_rn(accd[i][j], __fmul_rn(xv, wd4[j]));  // two-round
            accb[i][j] = __fadd_rn(accb[i][j], __fmul_rn(xv, wb4[j]));
          }
        }
      }
    }
  }
#undef ISSUE_LOADS

  // Epilogue (frozen numerics), float4 stores per output row.
  const int n0 = bn0 + tx * 4;
  float bd4[4], bb4[4], eA4[4];
#pragma unroll
  for (int j = 0; j < 4; ++j) {
    bd4[j] = bd[n0 + j];
    bb4[j] = bb[n0 + j];
    eA4[j] = np_expf(A_log[n0 + j]);   // np.exp(A_log): SIMD Pade
  }
#pragma unroll
  for (int i = 0; i < 8; ++i) {
    const int m = bm0 + mg * 8 + i;
    float av[4], bv[4];
#pragma unroll
    for (int j = 0; j < 4; ++j) {
      float z1b = __fadd_rn(accd[i][j], bd4[j]);
      float z2b = __fadd_rn(accb[i][j], bb4[j]);
      float delta = np_softplus(z1b);            // np.logaddexp(z1b, 0)
      float w  = __fmul_rn(delta, eA4[j]);
      av[j] = np_expf(-w);                       // np.exp: SIMD Pade
      bv[j] = __fmul_rn(delta, z2b);
    }
    *(float4*)&Aarr[(size_t)m * Dd + n0] = make_float4(av[0], av[1], av[2], av[3]);
    *(float4*)&Barr[(size_t)m * Dd + n0] = make_float4(bv[0], bv[1], bv[2], bv[3]);
  }
}

// ---------------------------------------------------------------------------
// Kernel 2: sequential spiking scan (frozen numerics), PF=32. Unchanged.
// ---------------------------------------------------------------------------
__global__ __launch_bounds__(64) void scan_np(
    const float* __restrict__ thr_arr, const float* __restrict__ h0,
    float* __restrict__ Aarr, float* __restrict__ Barr)
{
  const int bx = blockIdx.x;                       // 0..127
  const int b  = bx >> 4;                          // 0..7
  const int d  = ((bx & 15) << 6) + threadIdx.x;   // 0..1023

  const float thr = thr_arr[d];
  float h = h0[(size_t)b * Dd + d];

  float* Ap = Aarr + (size_t)b * Tt * Dd + d;
  float* Bp = Barr + (size_t)b * Tt * Dd + d;

  constexpr int PF = 32;
  float pa[PF], pb[PF];
#pragma unroll
  for (int k = 0; k < PF; ++k) {
    pa[k] = Ap[(size_t)k * Dd];
    pb[k] = Bp[(size_t)k * Dd];
  }

  for (int t0 = 0; t0 < Tt; t0 += PF) {
    const int t1 = t0 + PF;
    float na[PF], nb[PF];
    if (t1 < Tt) {
#pragma unroll
      for (int k = 0; k < PF; ++k) {
        na[k] = Ap[(size_t)(t1 + k) * Dd];
        nb[k] = Bp[(size_t)(t1 + k) * Dd];
      }
    }
#pragma unroll
    for (int k = 0; k < PF; ++k) {
      h = __fadd_rn(__fmul_rn(pa[k], h), pb[k]);
      const bool spike = __fsub_rn(h, thr) > 0.0f;
      h = spike ? 0.0f : h;
      Ap[(size_t)(t0 + k) * Dd] = h;
      Bp[(size_t)(t0 + k) * Dd] = spike ? 1.0f : 0.0f;
    }
    if (t1 < Tt) {
#pragma unroll
      for (int k = 0; k < PF; ++k) { pa[k] = na[k]; pb[k] = nb[k]; }
    }
  }
}

// ---------------------------------------------------------------------------
// Kernel 3: LayerNorm (fp64 stats). Unchanged.
// ---------------------------------------------------------------------------
__global__ __launch_bounds__(256) void ln_np(
    const float* __restrict__ gamma, const float* __restrict__ beta,
    float* __restrict__ H)
{
  const int row = blockIdx.x;
  const int tid = threadIdx.x;
  const size_t base = (size_t)row * Dd + (tid << 2);

  float4 v = *(const float4*)&H[base];

  __shared__ double red[4];
  __shared__ double red2[4];
  const int wave = tid >> 6, lane = tid & 63;

  double sum = (double)v.x + (double)v.y + (double)v.z + (double)v.w;
#pragma unroll
  for (int off = 32; off > 0; off >>= 1) sum += __shfl_down(sum, off);
  if (lane == 0) red[wave] = sum;
  __syncthreads();
  const float muf = (float)((red[0] + red[1] + red[2] + red[3]) * (1.0 / Dd));

  float dx0 = __fsub_rn(v.x, muf), dx1 = __fsub_rn(v.y, muf);
  float dx2 = __fsub_rn(v.z, muf), dx3 = __fsub_rn(v.w, muf);
  double sq = (double)dx0*dx0 + (double)dx1*dx1 + (double)dx2*dx2 + (double)dx3*dx3;
#pragma unroll
  for (int off = 32; off > 0; off >>= 1) sq += __shfl_down(sq, off);
  if (lane == 0) red2[wave] = sq;
  __syncthreads();
  const float varf = (float)((red2[0] + red2[1] + red2[2] + red2[3]) * (1.0 / Dd));
  const float invf = __fdiv_rn(1.0f, __fsqrt_rn(__fadd_rn(varf, 1e-5f)));

  const int n = tid << 2;
  float4 g  = *(const float4*)&gamma[n];
  float4 be = *(const float4*)&beta[n];
  float4 o;
  o.x = __fadd_rn(__fmul_rn(__fmul_rn(dx0, invf), g.x), be.x);
  o.y = __fadd_rn(__fmul_rn(__fmul_rn(dx1, invf), g.y), be.y);
  o.z = __fadd_rn(__fmul_rn(__fmul_rn(dx2, invf), g.z), be.z);
  o.w = __fadd_rn(__fmul_rn(__fmul_rn(dx3, invf), g.w), be.w);
  *(float4*)&H[base] = o;
}

// ---------------------------------------------------------------------------
extern "C" void kernel_launch(void* const* d_in, const int* in_sizes, int n_in,
                              void* d_out, int out_size, void* d_ws, size_t ws_size,
                              hipStream_t stream)
{
  const float* x     = (const float*)d_in[0];
  const float* Wd    = (const float*)d_in[1];
  const float* bd    = (const float*)d_in[2];
  const float* Wb    = (const float*)d_in[3];
  const float* bb    = (const float*)d_in[4];
  const float* A_log = (const float*)d_in[5];
  const float* thr   = (const float*)d_in[6];
  const float* gamma = (const float*)d_in[7];
  const float* beta  = (const float*)d_in[8];
  const float* h0    = (const float*)d_in[9];

  float* out  = (float*)d_out;
  float* Aarr = out;                  // A_step -> h_post -> LN out
  float* Barr = out + (size_t)BTD;    // b_step -> spikes

  dim3 g1(Dd / BN, (int)(BT / BM));   // (16, 128)
  gemm_np<<<g1, 256, 0, stream>>>(x, Wd, bd, Wb, bb, A_log, Aarr, Barr);
  scan_np<<<128, 64, 0, stream>>>(thr, h0, Aarr, Barr);
  ln_np<<<(int)BT, 256, 0, stream>>>(gamma, beta, Aarr);
}

// Round 13
// 1007.904 us; speedup vs baseline: 1.3496x; 1.3496x over previous
//
#include <hip/hip_runtime.h>
#include <cmath>

// Problem constants
constexpr int Bb  = 8;
constexpr int Tt  = 2048;
constexpr int DIN = 512;
constexpr int Dd  = 1024;
constexpr long long BT  = (long long)Bb * Tt;   // 16384
constexpr long long BTD = BT * Dd;              // 16777216

// ===== FROZEN NUMERICS (verified PASS rounds 9-12, absmax 0.03125) =========
__device__ __forceinline__ float np_expf(float x) {
  const float LOG2E = 1.4426950408889634074f;
  const float MAGIC = 12582912.0f;              // 0x1.8p23
  const float C1 = -6.93145752e-1f;
  const float C2 = -1.42860677e-6f;
  const float P0 = 9.999999999980870924916e-01f;
  const float P1 = 7.257664613233124478488e-01f;
  const float P2 = 2.473615434895520810817e-01f;
  const float P3 = 5.114512081637298353406e-02f;
  const float P4 = 6.757896990527504603057e-03f;
  const float P5 = 5.082762527590693718096e-04f;
  const float Q0 = 1.0f;
  const float Q1 = -2.742335390411667452936e-01f;
  const float Q2 = 2.159509375685829852307e-02f;
  const float XMAX = 88.72283935546875f;
  const float XMIN = -87.3365478515625f;
  if (!(x == x)) return x;
  if (x > XMAX)  return __builtin_inff();
  if (x < XMIN)  return 0.0f;
  float q = __fsub_rn(fmaf(x, LOG2E, MAGIC), MAGIC);
  float r = fmaf(q, C1, x);
  r = fmaf(q, C2, r);
  float num = fmaf(r, P5, P4);
  num = fmaf(num, r, P3);
  num = fmaf(num, r, P2);
  num = fmaf(num, r, P1);
  num = fmaf(num, r, P0);
  float den = fmaf(r, Q2, Q1);
  den = fmaf(den, r, Q0);
  float p = __fdiv_rn(num, den);
  return ldexpf(p, (int)q);
}

__device__ __forceinline__ float expf_cr(float x) { return (float)exp((double)x); }

__device__ __forceinline__ float log1pf_fd(float x) {
  const float ln2_hi = __int_as_float(0x3f317180);
  const float ln2_lo = __int_as_float(0x3717f7d1);
  const float Lp1 = __int_as_float(0x3F2AAAAB), Lp2 = __int_as_float(0x3ECCCCCD),
              Lp3 = __int_as_float(0x3E924925), Lp4 = __int_as_float(0x3E638E29),
              Lp5 = __int_as_float(0x3E3A3325), Lp6 = __int_as_float(0x3E1CD04F),
              Lp7 = __int_as_float(0x3E178897);
  int hx = __float_as_int(x);
  int ax = hx & 0x7fffffff;
  int k = 1, hu = 0;
  float f = 0.f, c = 0.f, u;
  if (hx < 0x3ed413d7) {
    if (ax < 0x38000000) {
      if (ax < 0x33800000) return x;
      return __fsub_rn(x, __fmul_rn(__fmul_rn(x, x), 0.5f));
    }
    if (hx > 0 || hx <= (int)0xbe95f61f) { k = 0; f = x; hu = 1; }
  }
  if (k != 0) {
    if (hx < 0x4b800000) {
      u = __fadd_rn(1.0f, x);
      int hu0 = __float_as_int(u);
      k = (hu0 >> 23) - 127;
      c = (k > 0) ? __fsub_rn(1.0f, __fsub_rn(u, x))
                  : __fsub_rn(x, __fsub_rn(u, 1.0f));
      c = __fdiv_rn(c, u);
      hu = hu0;
    } else {
      u = x; hu = __float_as_int(u); k = (hu >> 23) - 127; c = 0.f;
    }
    hu &= 0x007fffff;
    if (hu < 0x3504f7) { u = __int_as_float(hu | 0x3f800000); }
    else { k += 1; u = __int_as_float(hu | 0x3f000000); hu = (0x00800000 - hu) >> 2; }
    f = __fsub_rn(u, 1.0f);
  }
  float hfsq = __fmul_rn(__fmul_rn(0.5f, f), f);
  if (hu == 0) {
    if (f == 0.0f) {
      if (k == 0) return 0.0f;
      c = __fadd_rn(c, __fmul_rn((float)k, ln2_lo));
      return __fadd_rn(__fmul_rn((float)k, ln2_hi), c);
    }
    float R = __fmul_rn(hfsq, __fsub_rn(1.0f, __fmul_rn(0.66666668653f, f)));
    if (k == 0) return __fsub_rn(f, R);
    return __fsub_rn(__fmul_rn((float)k, ln2_hi),
           __fsub_rn(__fsub_rn(R, __fadd_rn(__fmul_rn((float)k, ln2_lo), c)), f));
  }
  float s = __fdiv_rn(f, __fadd_rn(2.0f, f));
  float z = __fmul_rn(s, s);
  float pz = __fadd_rn(Lp6, __fmul_rn(z, Lp7));
  pz = __fadd_rn(Lp5, __fmul_rn(z, pz));
  pz = __fadd_rn(Lp4, __fmul_rn(z, pz));
  pz = __fadd_rn(Lp3, __fmul_rn(z, pz));
  pz = __fadd_rn(Lp2, __fmul_rn(z, pz));
  pz = __fadd_rn(Lp1, __fmul_rn(z, pz));
  float R = __fmul_rn(z, pz);
  if (k == 0)
    return __fsub_rn(f, __fsub_rn(hfsq, __fmul_rn(s, __fadd_rn(hfsq, R))));
  return __fsub_rn(__fmul_rn((float)k, ln2_hi),
         __fsub_rn(__fsub_rn(hfsq, __fadd_rn(__fmul_rn(s, __fadd_rn(hfsq, R)),
                   __fadd_rn(__fmul_rn((float)k, ln2_lo), c))), f));
}

__device__ __forceinline__ float np_softplus(float x) {
  if (x == 0.0f) return __int_as_float(0x3F317218);
  if (x > 0.0f)  return __fadd_rn(x, log1pf_fd(expf_cr(-x)));
  return log1pf_fd(expf_cr(x));
}
// ===========================================================================

#define BM 128
#define BN 64
#define BK 32

// ---------------------------------------------------------------------------
// Kernel 1: dual GEMM — PURE ASCENDING TWO-ROUNDING CHAIN per output element.
// R12 structure (conflict-free swizzles + register-prefetch pipeline), but
// with the register cap REMOVED (R12's __launch_bounds__(256,4) forced
// 64 VGPR -> full accumulator spill -> 2GB scratch traffic, 2x slowdown).
// Per-element FP op sequence bit-identical to rounds 9-12.
// ---------------------------------------------------------------------------
__global__ __launch_bounds__(256) void gemm_np(
    const float* __restrict__ x,  const float* __restrict__ Wd,
    const float* __restrict__ bd, const float* __restrict__ Wb,
    const float* __restrict__ bb, const float* __restrict__ A_log,
    float* __restrict__ Aarr, float* __restrict__ Barr)
{
  __shared__ float xs[BM][BK];      // [m][k], quad-swizzled within row
  __shared__ float wds[BK][BN];     // [k][n], col = n ^ (kq<<2)
  __shared__ float wbs[BK][BN];

  const int tid = threadIdx.x;
  const int bn0 = blockIdx.x * BN;
  const int bm0 = blockIdx.y * BM;
  const int tx  = tid & 15;         // n-quad: cols tx*4 .. +3
  const int mg  = tid >> 4;         // m-group 0..15: rows mg*8 .. +7
  const int swz = mg & 7;           // x read swizzle key

  const int sr8 = tid >> 3;         // 0..31
  const int sq  = tid & 7;          // 0..7

  float accd[8][4], accb[8][4];
#pragma unroll
  for (int i = 0; i < 8; ++i)
#pragma unroll
    for (int j = 0; j < 4; ++j) { accd[i][j] = 0.f; accb[i][j] = 0.f; }

  // ---- prefetch registers (tile kt) ----
  float4 px0, px1, px2, px3, pd0, pd1, pb0, pb1;
#define ISSUE_LOADS(K0)                                                        \
  {                                                                            \
    const int k0_ = (K0);                                                      \
    px0 = *(const float4*)&x[(size_t)(bm0 +  0 + sr8) * DIN + k0_ + sq * 4];   \
    px1 = *(const float4*)&x[(size_t)(bm0 + 32 + sr8) * DIN + k0_ + sq * 4];   \
    px2 = *(const float4*)&x[(size_t)(bm0 + 64 + sr8) * DIN + k0_ + sq * 4];   \
    px3 = *(const float4*)&x[(size_t)(bm0 + 96 + sr8) * DIN + k0_ + sq * 4];   \
    pd0 = *(const float4*)&Wd[(size_t)(bn0 +  0 + sr8) * DIN + k0_ + sq * 4];  \
    pd1 = *(const float4*)&Wd[(size_t)(bn0 + 32 + sr8) * DIN + k0_ + sq * 4];  \
    pb0 = *(const float4*)&Wb[(size_t)(bn0 +  0 + sr8) * DIN + k0_ + sq * 4];  \
    pb1 = *(const float4*)&Wb[(size_t)(bn0 + 32 + sr8) * DIN + k0_ + sq * 4];  \
  }

  ISSUE_LOADS(0);

  for (int kt = 0; kt < DIN / BK; ++kt) {       // 16 k-tiles, ascending
    __syncthreads();                             // previous compute done
    // ---- write staged regs to LDS (conflict-free swizzles) ----
    {
      int r0 = sr8,      qs0 = sq ^ ((r0 >> 3) & 7);
      int r1 = 32 + sr8, qs1 = sq ^ ((r1 >> 3) & 7);
      int r2 = 64 + sr8, qs2 = sq ^ ((r2 >> 3) & 7);
      int r3 = 96 + sr8, qs3 = sq ^ ((r3 >> 3) & 7);
      *(float4*)&xs[r0][qs0 * 4] = px0;
      *(float4*)&xs[r1][qs1 * 4] = px1;
      *(float4*)&xs[r2][qs2 * 4] = px2;
      *(float4*)&xs[r3][qs3 * 4] = px3;
      int c0 = (sr8)      ^ (sq << 2);
      int c1 = (32 + sr8) ^ (sq << 2);
      wds[sq*4+0][c0] = pd0.x; wds[sq*4+1][c0] = pd0.y;
      wds[sq*4+2][c0] = pd0.z; wds[sq*4+3][c0] = pd0.w;
      wds[sq*4+0][c1] = pd1.x; wds[sq*4+1][c1] = pd1.y;
      wds[sq*4+2][c1] = pd1.z; wds[sq*4+3][c1] = pd1.w;
      wbs[sq*4+0][c0] = pb0.x; wbs[sq*4+1][c0] = pb0.y;
      wbs[sq*4+2][c0] = pb0.z; wbs[sq*4+3][c0] = pb0.w;
      wbs[sq*4+0][c1] = pb1.x; wbs[sq*4+1][c1] = pb1.y;
      wbs[sq*4+2][c1] = pb1.z; wbs[sq*4+3][c1] = pb1.w;
    }
    __syncthreads();

    // ---- issue next tile's loads (latency hides under compute) ----
    if (kt + 1 < DIN / BK) ISSUE_LOADS((kt + 1) * BK);

    // ---- compute on LDS tile kt ----
#pragma unroll
    for (int kq = 0; kq < BK / 4; ++kq) {        // 8 quads, ascending
      float xk[8][4];
#pragma unroll
      for (int i = 0; i < 8; ++i) {
        float4 v = *(const float4*)&xs[mg * 8 + i][(kq ^ swz) * 4];
        xk[i][0] = v.x; xk[i][1] = v.y; xk[i][2] = v.z; xk[i][3] = v.w;
      }
      const int wc = 4 * (tx ^ kq);
#pragma unroll
      for (int t = 0; t < 4; ++t) {              // k within quad, ascending
        float4 wdv = *(const float4*)&wds[kq * 4 + t][wc];
        float4 wbv = *(const float4*)&wbs[kq * 4 + t][wc];
        float wd4[4] = {wdv.x, wdv.y, wdv.z, wdv.w};
        float wb4[4] = {wbv.x, wbv.y, wbv.z, wbv.w};
#pragma unroll
        for (int i = 0; i < 8; ++i) {
          const float xv = xk[i][t];
#pragma unroll
          for (int j = 0; j < 4; ++j) {
            accd[i][j] = __fadd_rn(accd[i][j], __fmul_rn(xv, wd4[j]));  // two-round
            accb[i][j] = __fadd_rn(accb[i][j], __fmul_rn(xv, wb4[j]));
          }
        }
      }
    }
  }
#undef ISSUE_LOADS

  // Epilogue (frozen numerics), float4 stores per output row.
  const int n0 = bn0 + tx * 4;
  float bd4[4], bb4[4], eA4[4];
#pragma unroll
  for (int j = 0; j < 4; ++j) {
    bd4[j] = bd[n0 + j];
    bb4[j] = bb[n0 + j];
    eA4[j] = np_expf(A_log[n0 + j]);   // np.exp(A_log): SIMD Pade
  }
#pragma unroll
  for (int i = 0; i < 8; ++i) {
    const int m = bm0 + mg * 8 + i;
    float av[4], bv[4];
#pragma unroll
    for (int j = 0; j < 4; ++j) {
      float z1b = __fadd_rn(accd[i][j], bd4[j]);
      float z2b = __fadd_rn(accb[i][j], bb4[j]);
      float delta = np_softplus(z1b);            // np.logaddexp(z1b, 0)
      float w  = __fmul_rn(delta, eA4[j]);
      av[j] = np_expf(-w);                       // np.exp: SIMD Pade
      bv[j] = __fmul_rn(delta, z2b);
    }
    *(float4*)&Aarr[(size_t)m * Dd + n0] = make_float4(av[0], av[1], av[2], av[3]);
    *(float4*)&Barr[(size_t)m * Dd + n0] = make_float4(bv[0], bv[1], bv[2], bv[3]);
  }
}

// ---------------------------------------------------------------------------
// Kernel 2: sequential spiking scan (frozen numerics), PF=32. Unchanged.
// ---------------------------------------------------------------------------
__global__ __launch_bounds__(64) void scan_np(
    const float* __restrict__ thr_arr, const float* __restrict__ h0,
    float* __restrict__ Aarr, float* __restrict__ Barr)
{
  const int bx = blockIdx.x;                       // 0..127
  const int b  = bx >> 4;                          // 0..7
  const int d  = ((bx & 15) << 6) + threadIdx.x;   // 0..1023

  const float thr = thr_arr[d];
  float h = h0[(size_t)b * Dd + d];

  float* Ap = Aarr + (size_t)b * Tt * Dd + d;
  float* Bp = Barr + (size_t)b * Tt * Dd + d;

  constexpr int PF = 32;
  float pa[PF], pb[PF];
#pragma unroll
  for (int k = 0; k < PF; ++k) {
    pa[k] = Ap[(size_t)k * Dd];
    pb[k] = Bp[(size_t)k * Dd];
  }

  for (int t0 = 0; t0 < Tt; t0 += PF) {
    const int t1 = t0 + PF;
    float na[PF], nb[PF];
    if (t1 < Tt) {
#pragma unroll
      for (int k = 0; k < PF; ++k) {
        na[k] = Ap[(size_t)(t1 + k) * Dd];
        nb[k] = Bp[(size_t)(t1 + k) * Dd];
      }
    }
#pragma unroll
    for (int k = 0; k < PF; ++k) {
      h = __fadd_rn(__fmul_rn(pa[k], h), pb[k]);
      const bool spike = __fsub_rn(h, thr) > 0.0f;
      h = spike ? 0.0f : h;
      Ap[(size_t)(t0 + k) * Dd] = h;
      Bp[(size_t)(t0 + k) * Dd] = spike ? 1.0f : 0.0f;
    }
    if (t1 < Tt) {
#pragma unroll
      for (int k = 0; k < PF; ++k) { pa[k] = na[k]; pb[k] = nb[k]; }
    }
  }
}

// ---------------------------------------------------------------------------
// Kernel 3: LayerNorm (fp64 stats). Unchanged.
// ---------------------------------------------------------------------------
__global__ __launch_bounds__(256) void ln_np(
    const float* __restrict__ gamma, const float* __restrict__ beta,
    float* __restrict__ H)
{
  const int row = blockIdx.x;
  const int tid = threadIdx.x;
  const size_t base = (size_t)row * Dd + (tid << 2);

  float4 v = *(const float4*)&H[base];

  __shared__ double red[4];
  __shared__ double red2[4];
  const int wave = tid >> 6, lane = tid & 63;

  double sum = (double)v.x + (double)v.y + (double)v.z + (double)v.w;
#pragma unroll
  for (int off = 32; off > 0; off >>= 1) sum += __shfl_down(sum, off);
  if (lane == 0) red[wave] = sum;
  __syncthreads();
  const float muf = (float)((red[0] + red[1] + red[2] + red[3]) * (1.0 / Dd));

  float dx0 = __fsub_rn(v.x, muf), dx1 = __fsub_rn(v.y, muf);
  float dx2 = __fsub_rn(v.z, muf), dx3 = __fsub_rn(v.w, muf);
  double sq = (double)dx0*dx0 + (double)dx1*dx1 + (double)dx2*dx2 + (double)dx3*dx3;
#pragma unroll
  for (int off = 32; off > 0; off >>= 1) sq += __shfl_down(sq, off);
  if (lane == 0) red2[wave] = sq;
  __syncthreads();
  const float varf = (float)((red2[0] + red2[1] + red2[2] + red2[3]) * (1.0 / Dd));
  const float invf = __fdiv_rn(1.0f, __fsqrt_rn(__fadd_rn(varf, 1e-5f)));

  const int n = tid << 2;
  float4 g  = *(const float4*)&gamma[n];
  float4 be = *(const float4*)&beta[n];
  float4 o;
  o.x = __fadd_rn(__fmul_rn(__fmul_rn(dx0, invf), g.x), be.x);
  o.y = __fadd_rn(__fmul_rn(__fmul_rn(dx1, invf), g.y), be.y);
  o.z = __fadd_rn(__fmul_rn(__fmul_rn(dx2, invf), g.z), be.z);
  o.w = __fadd_rn(__fmul_rn(__fmul_rn(dx3, invf), g.w), be.w);
  *(float4*)&H[base] = o;
}

// ---------------------------------------------------------------------------
extern "C" void kernel_launch(void* const* d_in, const int* in_sizes, int n_in,
                              void* d_out, int out_size, void* d_ws, size_t ws_size,
                              hipStream_t stream)
{
  const float* x     = (const float*)d_in[0];
  const float* Wd    = (const float*)d_in[1];
  const float* bd    = (const float*)d_in[2];
  const float* Wb    = (const float*)d_in[3];
  const float* bb    = (const float*)d_in[4];
  const float* A_log = (const float*)d_in[5];
  const float* thr   = (const float*)d_in[6];
  const float* gamma = (const float*)d_in[7];
  const float* beta  = (const float*)d_in[8];
  const float* h0    = (const float*)d_in[9];

  float* out  = (float*)d_out;
  float* Aarr = out;                  // A_step -> h_post -> LN out
  float* Barr = out + (size_t)BTD;    // b_step -> spikes

  dim3 g1(Dd / BN, (int)(BT / BM));   // (16, 128)
  gemm_np<<<g1, 256, 0, stream>>>(x, Wd, bd, Wb, bb, A_log, Aarr, Barr);
  scan_np<<<128, 64, 0, stream>>>(thr, h0, Aarr, Barr);
  ln_np<<<(int)BT, 256, 0, stream>>>(gamma, beta, Aarr);
}

// Round 14
// 656.121 us; speedup vs baseline: 2.0731x; 1.5362x over previous
//
#include <hip/hip_runtime.h>
#include <cmath>

// Problem constants
constexpr int Bb  = 8;
constexpr int Tt  = 2048;
constexpr int DIN = 512;
constexpr int Dd  = 1024;
constexpr long long BT  = (long long)Bb * Tt;   // 16384
constexpr long long BTD = BT * Dd;              // 16777216

// ===== FROZEN NUMERICS (verified PASS rounds 9-13, absmax 0.03125) =========
__device__ __forceinline__ float np_expf(float x) {
  const float LOG2E = 1.4426950408889634074f;
  const float MAGIC = 12582912.0f;              // 0x1.8p23
  const float C1 = -6.93145752e-1f;
  const float C2 = -1.42860677e-6f;
  const float P0 = 9.999999999980870924916e-01f;
  const float P1 = 7.257664613233124478488e-01f;
  const float P2 = 2.473615434895520810817e-01f;
  const float P3 = 5.114512081637298353406e-02f;
  const float P4 = 6.757896990527504603057e-03f;
  const float P5 = 5.082762527590693718096e-04f;
  const float Q0 = 1.0f;
  const float Q1 = -2.742335390411667452936e-01f;
  const float Q2 = 2.159509375685829852307e-02f;
  const float XMAX = 88.72283935546875f;
  const float XMIN = -87.3365478515625f;
  if (!(x == x)) return x;
  if (x > XMAX)  return __builtin_inff();
  if (x < XMIN)  return 0.0f;
  float q = __fsub_rn(fmaf(x, LOG2E, MAGIC), MAGIC);
  float r = fmaf(q, C1, x);
  r = fmaf(q, C2, r);
  float num = fmaf(r, P5, P4);
  num = fmaf(num, r, P3);
  num = fmaf(num, r, P2);
  num = fmaf(num, r, P1);
  num = fmaf(num, r, P0);
  float den = fmaf(r, Q2, Q1);
  den = fmaf(den, r, Q0);
  float p = __fdiv_rn(num, den);
  return ldexpf(p, (int)q);
}

__device__ __forceinline__ float expf_cr(float x) { return (float)exp((double)x); }

__device__ __forceinline__ float log1pf_fd(float x) {
  const float ln2_hi = __int_as_float(0x3f317180);
  const float ln2_lo = __int_as_float(0x3717f7d1);
  const float Lp1 = __int_as_float(0x3F2AAAAB), Lp2 = __int_as_float(0x3ECCCCCD),
              Lp3 = __int_as_float(0x3E924925), Lp4 = __int_as_float(0x3E638E29),
              Lp5 = __int_as_float(0x3E3A3325), Lp6 = __int_as_float(0x3E1CD04F),
              Lp7 = __int_as_float(0x3E178897);
  int hx = __float_as_int(x);
  int ax = hx & 0x7fffffff;
  int k = 1, hu = 0;
  float f = 0.f, c = 0.f, u;
  if (hx < 0x3ed413d7) {
    if (ax < 0x38000000) {
      if (ax < 0x33800000) return x;
      return __fsub_rn(x, __fmul_rn(__fmul_rn(x, x), 0.5f));
    }
    if (hx > 0 || hx <= (int)0xbe95f61f) { k = 0; f = x; hu = 1; }
  }
  if (k != 0) {
    if (hx < 0x4b800000) {
      u = __fadd_rn(1.0f, x);
      int hu0 = __float_as_int(u);
      k = (hu0 >> 23) - 127;
      c = (k > 0) ? __fsub_rn(1.0f, __fsub_rn(u, x))
                  : __fsub_rn(x, __fsub_rn(u, 1.0f));
      c = __fdiv_rn(c, u);
      hu = hu0;
    } else {
      u = x; hu = __float_as_int(u); k = (hu >> 23) - 127; c = 0.f;
    }
    hu &= 0x007fffff;
    if (hu < 0x3504f7) { u = __int_as_float(hu | 0x3f800000); }
    else { k += 1; u = __int_as_float(hu | 0x3f000000); hu = (0x00800000 - hu) >> 2; }
    f = __fsub_rn(u, 1.0f);
  }
  float hfsq = __fmul_rn(__fmul_rn(0.5f, f), f);
  if (hu == 0) {
    if (f == 0.0f) {
      if (k == 0) return 0.0f;
      c = __fadd_rn(c, __fmul_rn((float)k, ln2_lo));
      return __fadd_rn(__fmul_rn((float)k, ln2_hi), c);
    }
    float R = __fmul_rn(hfsq, __fsub_rn(1.0f, __fmul_rn(0.66666668653f, f)));
    if (k == 0) return __fsub_rn(f, R);
    return __fsub_rn(__fmul_rn((float)k, ln2_hi),
           __fsub_rn(__fsub_rn(R, __fadd_rn(__fmul_rn((float)k, ln2_lo), c)), f));
  }
  float s = __fdiv_rn(f, __fadd_rn(2.0f, f));
  float z = __fmul_rn(s, s);
  float pz = __fadd_rn(Lp6, __fmul_rn(z, Lp7));
  pz = __fadd_rn(Lp5, __fmul_rn(z, pz));
  pz = __fadd_rn(Lp4, __fmul_rn(z, pz));
  pz = __fadd_rn(Lp3, __fmul_rn(z, pz));
  pz = __fadd_rn(Lp2, __fmul_rn(z, pz));
  pz = __fadd_rn(Lp1, __fmul_rn(z, pz));
  float R = __fmul_rn(z, pz);
  if (k == 0)
    return __fsub_rn(f, __fsub_rn(hfsq, __fmul_rn(s, __fadd_rn(hfsq, R))));
  return __fsub_rn(__fmul_rn((float)k, ln2_hi),
         __fsub_rn(__fsub_rn(hfsq, __fadd_rn(__fmul_rn(s, __fadd_rn(hfsq, R)),
                   __fadd_rn(__fmul_rn((float)k, ln2_lo), c))), f));
}

__device__ __forceinline__ float np_softplus(float x) {
  if (x == 0.0f) return __int_as_float(0x3F317218);
  if (x > 0.0f)  return __fadd_rn(x, log1pf_fd(expf_cr(-x)));
  return log1pf_fd(expf_cr(x));
}
// ===========================================================================

#define BM 128
#define BN 64
#define BK 32

// ---------------------------------------------------------------------------
// Kernel 1: dual GEMM — PURE ASCENDING TWO-ROUNDING CHAIN per output element.
// R10 loop structure (stage directly to LDS, short live ranges — implicit
// wave-level overlap hides latency; NO register-prefetch pipeline, which
// R13 showed costs 156 VGPR -> 12% occupancy -> 950us) combined with R13's
// conflict-free LDS swizzles (verified SQ_LDS_BANK_CONFLICT = 0):
//  - xs[m][k]: write quad qs = sq ^ ((row>>3)&7); read at (kq^swz)*4
//  - wds/wbs[k][col]: write col = n ^ (sq<<2);    read at 4*(tx^kq)
// Per-element FP op sequence bit-identical to rounds 9-13.
// ---------------------------------------------------------------------------
__global__ __launch_bounds__(256) void gemm_np(
    const float* __restrict__ x,  const float* __restrict__ Wd,
    const float* __restrict__ bd, const float* __restrict__ Wb,
    const float* __restrict__ bb, const float* __restrict__ A_log,
    float* __restrict__ Aarr, float* __restrict__ Barr)
{
  __shared__ float xs[BM][BK];      // [m][k], quad-swizzled within row
  __shared__ float wds[BK][BN];     // [k][n], col = n ^ (kq<<2)
  __shared__ float wbs[BK][BN];

  const int tid = threadIdx.x;
  const int bn0 = blockIdx.x * BN;
  const int bm0 = blockIdx.y * BM;
  const int tx  = tid & 15;         // n-quad: cols tx*4 .. +3
  const int mg  = tid >> 4;         // m-group 0..15: rows mg*8 .. +7
  const int swz = mg & 7;           // x read swizzle key

  const int sr8 = tid >> 3;         // 0..31
  const int sq  = tid & 7;          // 0..7
  // Precompute swizzled LDS write targets (loop-invariant)
  float* xdst0 = &xs[sr8     ][(sq ^ ((sr8 >> 3) & 7)) * 4];
  float* xdst1 = &xs[32 + sr8][(sq ^ (((32 + sr8) >> 3) & 7)) * 4];
  float* xdst2 = &xs[64 + sr8][(sq ^ (((64 + sr8) >> 3) & 7)) * 4];
  float* xdst3 = &xs[96 + sr8][(sq ^ (((96 + sr8) >> 3) & 7)) * 4];
  const int wc0 = (sr8)      ^ (sq << 2);
  const int wc1 = (32 + sr8) ^ (sq << 2);

  float accd[8][4], accb[8][4];
#pragma unroll
  for (int i = 0; i < 8; ++i)
#pragma unroll
    for (int j = 0; j < 4; ++j) { accd[i][j] = 0.f; accb[i][j] = 0.f; }

  for (int kt = 0; kt < DIN / BK; ++kt) {       // 16 k-tiles, ascending
    const int k0 = kt * BK;
    // loads -> immediately to LDS (short live ranges; waves overlap)
    float4 lx0 = *(const float4*)&x[(size_t)(bm0 +  0 + sr8) * DIN + k0 + sq * 4];
    float4 lx1 = *(const float4*)&x[(size_t)(bm0 + 32 + sr8) * DIN + k0 + sq * 4];
    float4 lx2 = *(const float4*)&x[(size_t)(bm0 + 64 + sr8) * DIN + k0 + sq * 4];
    float4 lx3 = *(const float4*)&x[(size_t)(bm0 + 96 + sr8) * DIN + k0 + sq * 4];
    float4 ld0 = *(const float4*)&Wd[(size_t)(bn0 +  0 + sr8) * DIN + k0 + sq * 4];
    float4 ld1 = *(const float4*)&Wd[(size_t)(bn0 + 32 + sr8) * DIN + k0 + sq * 4];
    float4 lb0 = *(const float4*)&Wb[(size_t)(bn0 +  0 + sr8) * DIN + k0 + sq * 4];
    float4 lb1 = *(const float4*)&Wb[(size_t)(bn0 + 32 + sr8) * DIN + k0 + sq * 4];
    __syncthreads();                             // prev compute done
    *(float4*)xdst0 = lx0;
    *(float4*)xdst1 = lx1;
    *(float4*)xdst2 = lx2;
    *(float4*)xdst3 = lx3;
    wds[sq*4+0][wc0] = ld0.x; wds[sq*4+1][wc0] = ld0.y;
    wds[sq*4+2][wc0] = ld0.z; wds[sq*4+3][wc0] = ld0.w;
    wds[sq*4+0][wc1] = ld1.x; wds[sq*4+1][wc1] = ld1.y;
    wds[sq*4+2][wc1] = ld1.z; wds[sq*4+3][wc1] = ld1.w;
    wbs[sq*4+0][wc0] = lb0.x; wbs[sq*4+1][wc0] = lb0.y;
    wbs[sq*4+2][wc0] = lb0.z; wbs[sq*4+3][wc0] = lb0.w;
    wbs[sq*4+0][wc1] = lb1.x; wbs[sq*4+1][wc1] = lb1.y;
    wbs[sq*4+2][wc1] = lb1.z; wbs[sq*4+3][wc1] = lb1.w;
    __syncthreads();

    // ---- compute on LDS tile kt ----
#pragma unroll
    for (int kq = 0; kq < BK / 4; ++kq) {        // 8 quads, ascending
      float xk[8][4];
#pragma unroll
      for (int i = 0; i < 8; ++i) {
        float4 v = *(const float4*)&xs[mg * 8 + i][(kq ^ swz) * 4];
        xk[i][0] = v.x; xk[i][1] = v.y; xk[i][2] = v.z; xk[i][3] = v.w;
      }
      const int wc = 4 * (tx ^ kq);
#pragma unroll
      for (int t = 0; t < 4; ++t) {              // k within quad, ascending
        float4 wdv = *(const float4*)&wds[kq * 4 + t][wc];
        float4 wbv = *(const float4*)&wbs[kq * 4 + t][wc];
        float wd4[4] = {wdv.x, wdv.y, wdv.z, wdv.w};
        float wb4[4] = {wbv.x, wbv.y, wbv.z, wbv.w};
#pragma unroll
        for (int i = 0; i < 8; ++i) {
          const float xv = xk[i][t];
#pragma unroll
          for (int j = 0; j < 4; ++j) {
            accd[i][j] = __fadd_rn(accd[i][j], __fmul_rn(xv, wd4[j]));  // two-round
            accb[i][j] = __fadd_rn(accb[i][j], __fmul_rn(xv, wb4[j]));
          }
        }
      }
    }
  }

  // Epilogue (frozen numerics), float4 stores per output row.
  const int n0 = bn0 + tx * 4;
  float bd4[4], bb4[4], eA4[4];
#pragma unroll
  for (int j = 0; j < 4; ++j) {
    bd4[j] = bd[n0 + j];
    bb4[j] = bb[n0 + j];
    eA4[j] = np_expf(A_log[n0 + j]);   // np.exp(A_log): SIMD Pade
  }
#pragma unroll
  for (int i = 0; i < 8; ++i) {
    const int m = bm0 + mg * 8 + i;
    float av[4], bv[4];
#pragma unroll
    for (int j = 0; j < 4; ++j) {
      float z1b = __fadd_rn(accd[i][j], bd4[j]);
      float z2b = __fadd_rn(accb[i][j], bb4[j]);
      float delta = np_softplus(z1b);            // np.logaddexp(z1b, 0)
      float w  = __fmul_rn(delta, eA4[j]);
      av[j] = np_expf(-w);                       // np.exp: SIMD Pade
      bv[j] = __fmul_rn(delta, z2b);
    }
    *(float4*)&Aarr[(size_t)m * Dd + n0] = make_float4(av[0], av[1], av[2], av[3]);
    *(float4*)&Barr[(size_t)m * Dd + n0] = make_float4(bv[0], bv[1], bv[2], bv[3]);
  }
}

// ---------------------------------------------------------------------------
// Kernel 2: sequential spiking scan (frozen numerics), PF=32. Unchanged.
// ---------------------------------------------------------------------------
__global__ __launch_bounds__(64) void scan_np(
    const float* __restrict__ thr_arr, const float* __restrict__ h0,
    float* __restrict__ Aarr, float* __restrict__ Barr)
{
  const int bx = blockIdx.x;                       // 0..127
  const int b  = bx >> 4;                          // 0..7
  const int d  = ((bx & 15) << 6) + threadIdx.x;   // 0..1023

  const float thr = thr_arr[d];
  float h = h0[(size_t)b * Dd + d];

  float* Ap = Aarr + (size_t)b * Tt * Dd + d;
  float* Bp = Barr + (size_t)b * Tt * Dd + d;

  constexpr int PF = 32;
  float pa[PF], pb[PF];
#pragma unroll
  for (int k = 0; k < PF; ++k) {
    pa[k] = Ap[(size_t)k * Dd];
    pb[k] = Bp[(size_t)k * Dd];
  }

  for (int t0 = 0; t0 < Tt; t0 += PF) {
    const int t1 = t0 + PF;
    float na[PF], nb[PF];
    if (t1 < Tt) {
#pragma unroll
      for (int k = 0; k < PF; ++k) {
        na[k] = Ap[(size_t)(t1 + k) * Dd];
        nb[k] = Bp[(size_t)(t1 + k) * Dd];
      }
    }
#pragma unroll
    for (int k = 0; k < PF; ++k) {
      h = __fadd_rn(__fmul_rn(pa[k], h), pb[k]);
      const bool spike = __fsub_rn(h, thr) > 0.0f;
      h = spike ? 0.0f : h;
      Ap[(size_t)(t0 + k) * Dd] = h;
      Bp[(size_t)(t0 + k) * Dd] = spike ? 1.0f : 0.0f;
    }
    if (t1 < Tt) {
#pragma unroll
      for (int k = 0; k < PF; ++k) { pa[k] = na[k]; pb[k] = nb[k]; }
    }
  }
}

// ---------------------------------------------------------------------------
// Kernel 3: LayerNorm (fp64 stats). Unchanged.
// ---------------------------------------------------------------------------
__global__ __launch_bounds__(256) void ln_np(
    const float* __restrict__ gamma, const float* __restrict__ beta,
    float* __restrict__ H)
{
  const int row = blockIdx.x;
  const int tid = threadIdx.x;
  const size_t base = (size_t)row * Dd + (tid << 2);

  float4 v = *(const float4*)&H[base];

  __shared__ double red[4];
  __shared__ double red2[4];
  const int wave = tid >> 6, lane = tid & 63;

  double sum = (double)v.x + (double)v.y + (double)v.z + (double)v.w;
#pragma unroll
  for (int off = 32; off > 0; off >>= 1) sum += __shfl_down(sum, off);
  if (lane == 0) red[wave] = sum;
  __syncthreads();
  const float muf = (float)((red[0] + red[1] + red[2] + red[3]) * (1.0 / Dd));

  float dx0 = __fsub_rn(v.x, muf), dx1 = __fsub_rn(v.y, muf);
  float dx2 = __fsub_rn(v.z, muf), dx3 = __fsub_rn(v.w, muf);
  double sq = (double)dx0*dx0 + (double)dx1*dx1 + (double)dx2*dx2 + (double)dx3*dx3;
#pragma unroll
  for (int off = 32; off > 0; off >>= 1) sq += __shfl_down(sq, off);
  if (lane == 0) red2[wave] = sq;
  __syncthreads();
  const float varf = (float)((red2[0] + red2[1] + red2[2] + red2[3]) * (1.0 / Dd));
  const float invf = __fdiv_rn(1.0f, __fsqrt_rn(__fadd_rn(varf, 1e-5f)));

  const int n = tid << 2;
  float4 g  = *(const float4*)&gamma[n];
  float4 be = *(const float4*)&beta[n];
  float4 o;
  o.x = __fadd_rn(__fmul_rn(__fmul_rn(dx0, invf), g.x), be.x);
  o.y = __fadd_rn(__fmul_rn(__fmul_rn(dx1, invf), g.y), be.y);
  o.z = __fadd_rn(__fmul_rn(__fmul_rn(dx2, invf), g.z), be.z);
  o.w = __fadd_rn(__fmul_rn(__fmul_rn(dx3, invf), g.w), be.w);
  *(float4*)&H[base] = o;
}

// ---------------------------------------------------------------------------
extern "C" void kernel_launch(void* const* d_in, const int* in_sizes, int n_in,
                              void* d_out, int out_size, void* d_ws, size_t ws_size,
                              hipStream_t stream)
{
  const float* x     = (const float*)d_in[0];
  const float* Wd    = (const float*)d_in[1];
  const float* bd    = (const float*)d_in[2];
  const float* Wb    = (const float*)d_in[3];
  const float* bb    = (const float*)d_in[4];
  const float* A_log = (const float*)d_in[5];
  const float* thr   = (const float*)d_in[6];
  const float* gamma = (const float*)d_in[7];
  const float* beta  = (const float*)d_in[8];
  const float* h0    = (const float*)d_in[9];

  float* out  = (float*)d_out;
  float* Aarr = out;                  // A_step -> h_post -> LN out
  float* Barr = out + (size_t)BTD;    // b_step -> spikes

  dim3 g1(Dd / BN, (int)(BT / BM));   // (16, 128)
  gemm_np<<<g1, 256, 0, stream>>>(x, Wd, bd, Wb, bb, A_log, Aarr, Barr);
  scan_np<<<128, 64, 0, stream>>>(thr, h0, Aarr, Barr);
  ln_np<<<(int)BT, 256, 0, stream>>>(gamma, beta, Aarr);
}